// Round 7
// baseline (358.978 us; speedup 1.0000x reference)
//
#include <hip/hip_runtime.h>
#include <hip/hip_bf16.h>

// Problem constants
#define BATCH 4
#define SEQ   2048
#define DIM   1024
#define HEADS 16
#define HD    64
#define ROWS  (BATCH * SEQ)   // 8192
#define QKV_N (3 * DIM)       // 3072
#define ATT_C 0.18033688011f  // 0.125 * log2(e)  (folded into Q at gemm1)

typedef unsigned short u16;
typedef _Float16 half8 __attribute__((ext_vector_type(8)));   // 8 f16 (4 VGPRs)
typedef _Float16 half4v __attribute__((ext_vector_type(4)));  // 8B packed store
typedef float f32x4 __attribute__((ext_vector_type(4)));      // MFMA accumulator

// async global->LDS, 16B per lane; LDS dest = wave-uniform base + lane*16
__device__ __forceinline__ void gload_lds16(const u16* g, u16* l) {
  typedef const __attribute__((address_space(1))) unsigned int* gp_t;
  typedef __attribute__((address_space(3))) unsigned int* lp_t;
  __builtin_amdgcn_global_load_lds((gp_t)(const void*)g, (lp_t)(void*)l, 16, 0, 0);
}

// ---------------------------------------------------------------------------
// conv_x: x fp32 [8192,1024] -> xh fp16 [8192,1024]
// ---------------------------------------------------------------------------
__global__ __launch_bounds__(256) void conv_x(const float* __restrict__ x,
                                              u16* __restrict__ xh) {
  int i = blockIdx.x * 256 + threadIdx.x;
  float4 v = ((const float4*)x)[i];
  half4v h = {(_Float16)v.x, (_Float16)v.y, (_Float16)v.z, (_Float16)v.w};
  *(half4v*)&xh[(size_t)i * 4] = h;
}

// ---------------------------------------------------------------------------
// conv_w: W fp32 [K,N] -> Wt fp16 [N,K] transposed
// ---------------------------------------------------------------------------
__global__ __launch_bounds__(256) void conv_w(const float* __restrict__ W,
                                              u16* __restrict__ Wt,
                                              int K, int N) {
  __shared__ float T[64][65];
  const int tid = threadIdx.x;
  const int k0 = blockIdx.y * 64, n0 = blockIdx.x * 64;
#pragma unroll
  for (int j = 0; j < 4; ++j) {
    int k = j * 16 + (tid >> 4), n4 = (tid & 15) * 4;
    float4 v = *(const float4*)(W + (size_t)(k0 + k) * N + n0 + n4);
    T[k][n4 + 0] = v.x; T[k][n4 + 1] = v.y; T[k][n4 + 2] = v.z; T[k][n4 + 3] = v.w;
  }
  __syncthreads();
#pragma unroll
  for (int j = 0; j < 4; ++j) {
    int n = j * 16 + (tid >> 4), k4 = (tid & 15) * 4;
    half4v w = {(_Float16)T[k4 + 0][n], (_Float16)T[k4 + 1][n],
                (_Float16)T[k4 + 2][n], (_Float16)T[k4 + 3][n]};
    *(half4v*)&Wt[(size_t)(n0 + n) * K + k0 + k4] = w;
  }
}

// ---------------------------------------------------------------------------
// m97-style fp16 MFMA GEMM: C = A[M,K] @ Bt[N,K]^T, fp32 accum.
// MODE 0: fp32 out + bias (out-projection).
// MODE 1: repack epilogue -> Qg (pre-scaled by ATT_C) / Kg / VtG, fp16.
// ---------------------------------------------------------------------------
template <int MODE>
__global__ __launch_bounds__(256) void gemm_bt(
    const u16* __restrict__ A, const u16* __restrict__ Bt,
    const float* __restrict__ bias, void* __restrict__ Cv,
    u16* __restrict__ Qg, u16* __restrict__ Kg, u16* __restrict__ VtG,
    int M, int N, int K) {
  __shared__ u16 As[128 * 32];
  __shared__ u16 Bs[128 * 32];

  const int tid = threadIdx.x;
  const int wave = tid >> 6, lane = tid & 63;
  const int q4 = lane >> 4, c = lane & 15;
  const int wm = wave >> 1, wn = wave & 1;
  const int row0 = blockIdx.y * 128, col0 = blockIdx.x * 128;
  const int rr = lane >> 2, seg = lane & 3;

  f32x4 acc[4][4];
#pragma unroll
  for (int mi = 0; mi < 4; ++mi)
#pragma unroll
    for (int ni = 0; ni < 4; ++ni) acc[mi][ni] = (f32x4){0.f, 0.f, 0.f, 0.f};

  for (int k0 = 0; k0 < K; k0 += 32) {
#pragma unroll
    for (int i = 0; i < 2; ++i) {
      int chunk = wave * 2 + i;
      gload_lds16(A + (size_t)(row0 + chunk * 16 + rr) * K + k0 + seg * 8,
                  &As[chunk * 512]);
      gload_lds16(Bt + (size_t)(col0 + chunk * 16 + rr) * K + k0 + seg * 8,
                  &Bs[chunk * 512]);
    }
    __syncthreads();

    half8 af[4], bf[4];
#pragma unroll
    for (int mi = 0; mi < 4; ++mi)
      af[mi] = *(const half8*)&As[(wm * 64 + mi * 16 + c) * 32 + q4 * 8];
#pragma unroll
    for (int ni = 0; ni < 4; ++ni)
      bf[ni] = *(const half8*)&Bs[(wn * 64 + ni * 16 + c) * 32 + q4 * 8];
#pragma unroll
    for (int mi = 0; mi < 4; ++mi)
#pragma unroll
      for (int ni = 0; ni < 4; ++ni)
        acc[mi][ni] = __builtin_amdgcn_mfma_f32_16x16x32_f16(
            af[mi], bf[ni], acc[mi][ni], 0, 0, 0);
    __syncthreads();
  }

#pragma unroll
  for (int mi = 0; mi < 4; ++mi)
#pragma unroll
    for (int ni = 0; ni < 4; ++ni) {
      int colg = col0 + wn * 64 + ni * 16 + c;
      if (MODE == 0) {
        float bv = bias[colg];
#pragma unroll
        for (int r = 0; r < 4; ++r) {
          int rowg = row0 + wm * 64 + mi * 16 + q4 * 4 + r;
          ((float*)Cv)[(size_t)rowg * N + colg] = acc[mi][ni][r] + bv;
        }
      } else {
        int rowg0 = row0 + wm * 64 + mi * 16 + q4 * 4;   // 4 consecutive tokens
        int b  = rowg0 >> 11;
        int which = colg >> 10;            // 0=Q 1=K 2=V (uniform per block)
        int rem = colg & 1023;
        int hh = rem >> 6, d = rem & 63;
        size_t bh = (size_t)(b * HEADS + hh);
        if (which == 2) {
          int i0 = rowg0 & 2047;
          half4v pv = {(_Float16)acc[mi][ni][0], (_Float16)acc[mi][ni][1],
                       (_Float16)acc[mi][ni][2], (_Float16)acc[mi][ni][3]};
          *(half4v*)&VtG[(bh * HD + d) * SEQ + i0] = pv;
        } else {
          u16* dst = (which == 0) ? Qg : Kg;
          float sc = (which == 0) ? ATT_C : 1.0f;   // fold softmax scale into Q
#pragma unroll
          for (int r = 0; r < 4; ++r) {
            int i = (rowg0 + r) & 2047;
            ((_Float16*)dst)[(bh * SEQ + i) * HD + d] =
                (_Float16)(acc[mi][ni][r] * sc);
          }
        }
      }
    }
}

// ---------------------------------------------------------------------------
// Flash attention fp16, Q-tile=128, j-tile=64, no-max softmax.
// S^T = K·(Q*c)^T; Q fragments loaded DIRECTLY global->registers (no LDS
// staging buffer: Q is loop-invariant). LDS = Ks+Vt+Ps+l = 37.4 KB ->
// 4 blocks/CU, matching the 1024-block grid exactly (all co-resident).
// K/V staging via global_load_lds with XOR seg-swizzle (2-way, free).
// Grid: 1-D 1024, bh = L&63 -> same-head blocks stride 64 = same XCD (%8).
// ---------------------------------------------------------------------------
__global__ __launch_bounds__(256, 4) void attn_mfma(
    const u16* __restrict__ Qg, const u16* __restrict__ Kg,
    const u16* __restrict__ VtG, u16* __restrict__ ctx) {
  const int L  = blockIdx.x;       // 0..1023
  const int bh = L & 63;
  const int b  = bh >> 4, h = bh & 15;
  const int qt = L >> 6;           // 0..15

  __shared__ u16 Ks[2][64 * 32];   // 8 KB
  __shared__ u16 Vt[2][64 * 32];   // 8 KB
  __shared__ u16 Ps[128 * 72];     // 18.4 KB
  __shared__ float lred[4][128];   // 2 KB
  __shared__ float lfull[128];     // 0.5 KB

  const int tid  = threadIdx.x;
  const int wave = tid >> 6;
  const int lane = tid & 63;
  const int q4   = lane >> 4;
  const int c    = lane & 15;
  const int rr   = lane >> 2, seg = lane & 3;
  const int sseg = seg ^ (rr & 3);       // staging-side XOR swizzle
  const int rsw  = (c & 3);              // read-side counter-swizzle

  const size_t bhb = (size_t)bh;
  const int qrow0 = qt * 128;

  // ---- Q fragments: direct global->register (one-time, loop-invariant) ----
  // B-operand layout: B[n = i = nt*16+c][k = d = half*32 + q4*8 + 0..7]
  half8 qf[8][2];
#pragma unroll
  for (int nt = 0; nt < 8; ++nt)
#pragma unroll
    for (int half = 0; half < 2; ++half)
      qf[nt][half] = *(const half8*)&Qg[(bhb * SEQ + qrow0 + nt * 16 + c) * HD
                                        + half * 32 + q4 * 8];

  f32x4 o_acc[2][4];
#pragma unroll
  for (int sub = 0; sub < 2; ++sub)
#pragma unroll
    for (int dt = 0; dt < 4; ++dt) o_acc[sub][dt] = (f32x4){0.f, 0.f, 0.f, 0.f};
  float lp[8] = {0.f, 0.f, 0.f, 0.f, 0.f, 0.f, 0.f, 0.f};

  for (int j0 = 0; j0 < SEQ; j0 += 64) {
    __syncthreads();   // prior iter's Ks/Vt/Ps reads complete
#pragma unroll
    for (int half = 0; half < 2; ++half) {
      gload_lds16(Kg + (bhb * SEQ + j0 + wave * 16 + rr) * HD
                      + half * 32 + sseg * 8,
                  &Ks[half][wave * 16 * 32]);
      gload_lds16(VtG + (bhb * HD + wave * 16 + rr) * SEQ + j0
                      + half * 32 + sseg * 8,
                  &Vt[half][wave * 16 * 32]);
    }
    __syncthreads();   // staging done (vmcnt drained)

    // ---- St = K·Q^T : wave owns 16 j-rows; softmax fused per nt ----
    half8 af0 = *(const half8*)&Ks[0][(wave * 16 + c) * 32 + (q4 ^ rsw) * 8];
    half8 af1 = *(const half8*)&Ks[1][(wave * 16 + c) * 32 + (q4 ^ rsw) * 8];
#pragma unroll
    for (int nt = 0; nt < 8; ++nt) {
      f32x4 st = (f32x4){0.f, 0.f, 0.f, 0.f};
      st = __builtin_amdgcn_mfma_f32_16x16x32_f16(af0, qf[nt][0], st, 0, 0, 0);
      st = __builtin_amdgcn_mfma_f32_16x16x32_f16(af1, qf[nt][1], st, 0, 0, 0);
      float p0 = __builtin_amdgcn_exp2f(st[0]);
      float p1 = __builtin_amdgcn_exp2f(st[1]);
      float p2 = __builtin_amdgcn_exp2f(st[2]);
      float p3 = __builtin_amdgcn_exp2f(st[3]);
      lp[nt] += (p0 + p1) + (p2 + p3);
      half4v w = {(_Float16)p0, (_Float16)p1, (_Float16)p2, (_Float16)p3};
      // Ps[i][j]: i = nt*16+c, j = wave*16 + q4*4 + 0..3
      *(half4v*)&Ps[(nt * 16 + c) * 72 + wave * 16 + q4 * 4] = w;
    }
    __syncthreads();   // Ps visible (Ks fully consumed above)

    // ---- O += P·V : wave owns 32 i-rows; V frags shared across subs ----
    half8 vb0[4], vb1[4];
#pragma unroll
    for (int dt = 0; dt < 4; ++dt) {
      vb0[dt] = *(const half8*)&Vt[0][(dt * 16 + c) * 32 + (q4 ^ rsw) * 8];
      vb1[dt] = *(const half8*)&Vt[1][(dt * 16 + c) * 32 + (q4 ^ rsw) * 8];
    }
#pragma unroll
    for (int sub = 0; sub < 2; ++sub) {
      half8 pa0 = *(const half8*)&Ps[(wave * 32 + sub * 16 + c) * 72 + q4 * 8];
      half8 pa1 = *(const half8*)&Ps[(wave * 32 + sub * 16 + c) * 72 + 32 + q4 * 8];
#pragma unroll
      for (int dt = 0; dt < 4; ++dt) {
        o_acc[sub][dt] = __builtin_amdgcn_mfma_f32_16x16x32_f16(
            pa0, vb0[dt], o_acc[sub][dt], 0, 0, 0);
        o_acc[sub][dt] = __builtin_amdgcn_mfma_f32_16x16x32_f16(
            pa1, vb1[dt], o_acc[sub][dt], 0, 0, 0);
      }
    }
  }

  // ---- l: reduce over q4 (same i, disjoint j), then across waves ----
#pragma unroll
  for (int nt = 0; nt < 8; ++nt) {
    lp[nt] += __shfl_xor(lp[nt], 16);
    lp[nt] += __shfl_xor(lp[nt], 32);
  }
  if (q4 == 0)
#pragma unroll
    for (int nt = 0; nt < 8; ++nt) lred[wave][nt * 16 + c] = lp[nt];
  __syncthreads();
  if (tid < 128)
    lfull[tid] = lred[0][tid] + lred[1][tid] + lred[2][tid] + lred[3][tid];
  __syncthreads();

  // ---- Finalize: O[i][d] /= l[i], store fp16 ctx[token][h*64+d] ----
#pragma unroll
  for (int sub = 0; sub < 2; ++sub)
#pragma unroll
    for (int r = 0; r < 4; ++r) {
      int i = wave * 32 + sub * 16 + q4 * 4 + r;
      float inv = 1.0f / lfull[i];
      size_t row = (size_t)b * SEQ + qrow0 + i;
#pragma unroll
      for (int dt = 0; dt < 4; ++dt)
        ((_Float16*)ctx)[row * DIM + h * HD + dt * 16 + c] =
            (_Float16)(o_acc[sub][dt][r] * inv);
    }
}

// ---------------------------------------------------------------------------
extern "C" void kernel_launch(void* const* d_in, const int* in_sizes, int n_in,
                              void* d_out, int out_size, void* d_ws, size_t ws_size,
                              hipStream_t stream) {
  const float* x    = (const float*)d_in[0];
  const float* Wqkv = (const float*)d_in[1];
  const float* Wout = (const float*)d_in[2];
  const float* bout = (const float*)d_in[3];
  float* out = (float*)d_out;

  // workspace (fp16 as u16), ~92 MB total
  u16* xh   = (u16*)d_ws;                              // [8192,1024]
  u16* Wqt  = xh  + (size_t)ROWS * DIM;                // [3072,1024]
  u16* Wot  = Wqt + (size_t)QKV_N * DIM;               // [1024,1024]
  u16* Qg   = Wot + (size_t)DIM * DIM;                 // [64,2048,64] (×ATT_C)
  u16* Kg   = Qg  + (size_t)BATCH * HEADS * SEQ * HD;  // [64,2048,64]
  u16* VtG  = Kg  + (size_t)BATCH * HEADS * SEQ * HD;  // [64,64,2048]
  u16* ctxh = VtG + (size_t)BATCH * HEADS * HD * SEQ;  // [8192,1024]

  conv_x<<<ROWS * DIM / 4 / 256, 256, 0, stream>>>(x, xh);
  conv_w<<<dim3(QKV_N / 64, DIM / 64), 256, 0, stream>>>(Wqkv, Wqt, DIM, QKV_N);
  conv_w<<<dim3(DIM / 64, DIM / 64), 256, 0, stream>>>(Wout, Wot, DIM, DIM);

  // 1) qkv = x @ Wqkv (fp16 MFMA), repack -> Qg (×ATT_C) / Kg / VtG
  gemm_bt<1><<<dim3(QKV_N / 128, ROWS / 128), 256, 0, stream>>>(
      xh, Wqt, nullptr, nullptr, Qg, Kg, VtG, ROWS, QKV_N, DIM);

  // 2) attention -> ctxh (fp16), Q-tile 128, 4 blocks/CU co-resident
  attn_mfma<<<dim3(1024), 256, 0, stream>>>(Qg, Kg, VtG, ctxh);

  // 3) out = ctx @ Wout + bout (fp32)
  gemm_bt<0><<<dim3(DIM / 128, ROWS / 128), 256, 0, stream>>>(
      ctxh, Wot, bout, out, nullptr, nullptr, nullptr, ROWS, DIM, DIM);
}

// Round 8
// 313.195 us; speedup vs baseline: 1.1462x; 1.1462x over previous
//
#include <hip/hip_runtime.h>
#include <hip/hip_bf16.h>

// Problem constants
#define BATCH 4
#define SEQ   2048
#define DIM   1024
#define HEADS 16
#define HD    64
#define ROWS  (BATCH * SEQ)   // 8192
#define QKV_N (3 * DIM)       // 3072
#define ATT_C 0.18033688011f  // 0.125 * log2(e)  (folded into Q at gemm1)

typedef unsigned short u16;
typedef _Float16 half8 __attribute__((ext_vector_type(8)));   // 8 f16 (4 VGPRs)
typedef _Float16 half4v __attribute__((ext_vector_type(4)));  // 8B packed store
typedef float f32x4 __attribute__((ext_vector_type(4)));      // MFMA accumulator

// async global->LDS, 16B per lane; LDS dest = wave-uniform base + lane*16
__device__ __forceinline__ void gload_lds16(const u16* g, u16* l) {
  typedef const __attribute__((address_space(1))) unsigned int* gp_t;
  typedef __attribute__((address_space(3))) unsigned int* lp_t;
  __builtin_amdgcn_global_load_lds((gp_t)(const void*)g, (lp_t)(void*)l, 16, 0, 0);
}

// ---------------------------------------------------------------------------
// conv_x: x fp32 [8192,1024] -> xh fp16 [8192,1024]
// ---------------------------------------------------------------------------
__global__ __launch_bounds__(256) void conv_x(const float* __restrict__ x,
                                              u16* __restrict__ xh) {
  int i = blockIdx.x * 256 + threadIdx.x;
  float4 v = ((const float4*)x)[i];
  half4v h = {(_Float16)v.x, (_Float16)v.y, (_Float16)v.z, (_Float16)v.w};
  *(half4v*)&xh[(size_t)i * 4] = h;
}

// ---------------------------------------------------------------------------
// conv_w: W fp32 [K,N] -> Wt fp16 [N,K] transposed
// ---------------------------------------------------------------------------
__global__ __launch_bounds__(256) void conv_w(const float* __restrict__ W,
                                              u16* __restrict__ Wt,
                                              int K, int N) {
  __shared__ float T[64][65];
  const int tid = threadIdx.x;
  const int k0 = blockIdx.y * 64, n0 = blockIdx.x * 64;
#pragma unroll
  for (int j = 0; j < 4; ++j) {
    int k = j * 16 + (tid >> 4), n4 = (tid & 15) * 4;
    float4 v = *(const float4*)(W + (size_t)(k0 + k) * N + n0 + n4);
    T[k][n4 + 0] = v.x; T[k][n4 + 1] = v.y; T[k][n4 + 2] = v.z; T[k][n4 + 3] = v.w;
  }
  __syncthreads();
#pragma unroll
  for (int j = 0; j < 4; ++j) {
    int n = j * 16 + (tid >> 4), k4 = (tid & 15) * 4;
    half4v w = {(_Float16)T[k4 + 0][n], (_Float16)T[k4 + 1][n],
                (_Float16)T[k4 + 2][n], (_Float16)T[k4 + 3][n]};
    *(half4v*)&Wt[(size_t)(n0 + n) * K + k0 + k4] = w;
  }
}

// ---------------------------------------------------------------------------
// m97-style fp16 MFMA GEMM: C = A[M,K] @ Bt[N,K]^T, fp32 accum.
// MODE 0: fp32 out + bias (out-projection).
// MODE 1: repack epilogue -> Qg (pre-scaled by ATT_C) / Kg / VtG, fp16.
// ---------------------------------------------------------------------------
template <int MODE>
__global__ __launch_bounds__(256) void gemm_bt(
    const u16* __restrict__ A, const u16* __restrict__ Bt,
    const float* __restrict__ bias, void* __restrict__ Cv,
    u16* __restrict__ Qg, u16* __restrict__ Kg, u16* __restrict__ VtG,
    int M, int N, int K) {
  __shared__ u16 As[128 * 32];
  __shared__ u16 Bs[128 * 32];

  const int tid = threadIdx.x;
  const int wave = tid >> 6, lane = tid & 63;
  const int q4 = lane >> 4, c = lane & 15;
  const int wm = wave >> 1, wn = wave & 1;
  const int row0 = blockIdx.y * 128, col0 = blockIdx.x * 128;
  const int rr = lane >> 2, seg = lane & 3;

  f32x4 acc[4][4];
#pragma unroll
  for (int mi = 0; mi < 4; ++mi)
#pragma unroll
    for (int ni = 0; ni < 4; ++ni) acc[mi][ni] = (f32x4){0.f, 0.f, 0.f, 0.f};

  for (int k0 = 0; k0 < K; k0 += 32) {
#pragma unroll
    for (int i = 0; i < 2; ++i) {
      int chunk = wave * 2 + i;
      gload_lds16(A + (size_t)(row0 + chunk * 16 + rr) * K + k0 + seg * 8,
                  &As[chunk * 512]);
      gload_lds16(Bt + (size_t)(col0 + chunk * 16 + rr) * K + k0 + seg * 8,
                  &Bs[chunk * 512]);
    }
    __syncthreads();

    half8 af[4], bf[4];
#pragma unroll
    for (int mi = 0; mi < 4; ++mi)
      af[mi] = *(const half8*)&As[(wm * 64 + mi * 16 + c) * 32 + q4 * 8];
#pragma unroll
    for (int ni = 0; ni < 4; ++ni)
      bf[ni] = *(const half8*)&Bs[(wn * 64 + ni * 16 + c) * 32 + q4 * 8];
#pragma unroll
    for (int mi = 0; mi < 4; ++mi)
#pragma unroll
      for (int ni = 0; ni < 4; ++ni)
        acc[mi][ni] = __builtin_amdgcn_mfma_f32_16x16x32_f16(
            af[mi], bf[ni], acc[mi][ni], 0, 0, 0);
    __syncthreads();
  }

#pragma unroll
  for (int mi = 0; mi < 4; ++mi)
#pragma unroll
    for (int ni = 0; ni < 4; ++ni) {
      int colg = col0 + wn * 64 + ni * 16 + c;
      if (MODE == 0) {
        float bv = bias[colg];
#pragma unroll
        for (int r = 0; r < 4; ++r) {
          int rowg = row0 + wm * 64 + mi * 16 + q4 * 4 + r;
          ((float*)Cv)[(size_t)rowg * N + colg] = acc[mi][ni][r] + bv;
        }
      } else {
        int rowg0 = row0 + wm * 64 + mi * 16 + q4 * 4;   // 4 consecutive tokens
        int b  = rowg0 >> 11;
        int which = colg >> 10;            // 0=Q 1=K 2=V (uniform per block)
        int rem = colg & 1023;
        int hh = rem >> 6, d = rem & 63;
        size_t bh = (size_t)(b * HEADS + hh);
        if (which == 2) {
          int i0 = rowg0 & 2047;
          half4v pv = {(_Float16)acc[mi][ni][0], (_Float16)acc[mi][ni][1],
                       (_Float16)acc[mi][ni][2], (_Float16)acc[mi][ni][3]};
          *(half4v*)&VtG[(bh * HD + d) * SEQ + i0] = pv;
        } else {
          u16* dst = (which == 0) ? Qg : Kg;
          float sc = (which == 0) ? ATT_C : 1.0f;   // fold softmax scale into Q
#pragma unroll
          for (int r = 0; r < 4; ++r) {
            int i = (rowg0 + r) & 2047;
            ((_Float16*)dst)[(bh * SEQ + i) * HD + d] =
                (_Float16)(acc[mi][ni][r] * sc);
          }
        }
      }
    }
}

// ---------------------------------------------------------------------------
// Flash attention fp16, Q-tile=128, j-tile=64, no-max softmax.
// S^T = K·(Q*c)^T; Q fragments loaded DIRECTLY global->registers (no LDS
// staging buffer: Q is loop-invariant). LDS = Ks+Vt+Ps+l = 37.4 KB.
// __launch_bounds__(256,3): register budget ~170 so the 64-VGPR Q-fragment
// array + accumulators FIT (bounds(256,4)=128 budget spilled to scratch:
// R7 showed FETCH 356 MB / WRITE 48 MB of spill traffic. Do not raise.)
// K/V staging via global_load_lds with XOR seg-swizzle (2-way, free).
// Grid: 1-D 1024, bh = L&63 -> same-head blocks land on one XCD (%8).
// ---------------------------------------------------------------------------
__global__ __launch_bounds__(256, 3) void attn_mfma(
    const u16* __restrict__ Qg, const u16* __restrict__ Kg,
    const u16* __restrict__ VtG, u16* __restrict__ ctx) {
  const int L  = blockIdx.x;       // 0..1023
  const int bh = L & 63;
  const int b  = bh >> 4, h = bh & 15;
  const int qt = L >> 6;           // 0..15

  __shared__ u16 Ks[2][64 * 32];   // 8 KB
  __shared__ u16 Vt[2][64 * 32];   // 8 KB
  __shared__ u16 Ps[128 * 72];     // 18.4 KB
  __shared__ float lred[4][128];   // 2 KB
  __shared__ float lfull[128];     // 0.5 KB

  const int tid  = threadIdx.x;
  const int wave = tid >> 6;
  const int lane = tid & 63;
  const int q4   = lane >> 4;
  const int c    = lane & 15;
  const int rr   = lane >> 2, seg = lane & 3;
  const int sseg = seg ^ (rr & 3);       // staging-side XOR swizzle
  const int rsw  = (c & 3);              // read-side counter-swizzle

  const size_t bhb = (size_t)bh;
  const int qrow0 = qt * 128;

  // ---- Q fragments: direct global->register (one-time, loop-invariant) ----
  // B-operand layout: B[n = i = nt*16+c][k = d = half*32 + q4*8 + 0..7]
  half8 qf[8][2];
#pragma unroll
  for (int nt = 0; nt < 8; ++nt)
#pragma unroll
    for (int half = 0; half < 2; ++half)
      qf[nt][half] = *(const half8*)&Qg[(bhb * SEQ + qrow0 + nt * 16 + c) * HD
                                        + half * 32 + q4 * 8];

  f32x4 o_acc[2][4];
#pragma unroll
  for (int sub = 0; sub < 2; ++sub)
#pragma unroll
    for (int dt = 0; dt < 4; ++dt) o_acc[sub][dt] = (f32x4){0.f, 0.f, 0.f, 0.f};
  float lp[8] = {0.f, 0.f, 0.f, 0.f, 0.f, 0.f, 0.f, 0.f};

  for (int j0 = 0; j0 < SEQ; j0 += 64) {
    __syncthreads();   // prior iter's Ks/Vt/Ps reads complete
#pragma unroll
    for (int half = 0; half < 2; ++half) {
      gload_lds16(Kg + (bhb * SEQ + j0 + wave * 16 + rr) * HD
                      + half * 32 + sseg * 8,
                  &Ks[half][wave * 16 * 32]);
      gload_lds16(VtG + (bhb * HD + wave * 16 + rr) * SEQ + j0
                      + half * 32 + sseg * 8,
                  &Vt[half][wave * 16 * 32]);
    }
    __syncthreads();   // staging done (vmcnt drained)

    // ---- St = K·Q^T : wave owns 16 j-rows; softmax fused per nt ----
    half8 af0 = *(const half8*)&Ks[0][(wave * 16 + c) * 32 + (q4 ^ rsw) * 8];
    half8 af1 = *(const half8*)&Ks[1][(wave * 16 + c) * 32 + (q4 ^ rsw) * 8];
#pragma unroll
    for (int nt = 0; nt < 8; ++nt) {
      f32x4 st = (f32x4){0.f, 0.f, 0.f, 0.f};
      st = __builtin_amdgcn_mfma_f32_16x16x32_f16(af0, qf[nt][0], st, 0, 0, 0);
      st = __builtin_amdgcn_mfma_f32_16x16x32_f16(af1, qf[nt][1], st, 0, 0, 0);
      float p0 = __builtin_amdgcn_exp2f(st[0]);
      float p1 = __builtin_amdgcn_exp2f(st[1]);
      float p2 = __builtin_amdgcn_exp2f(st[2]);
      float p3 = __builtin_amdgcn_exp2f(st[3]);
      lp[nt] += (p0 + p1) + (p2 + p3);
      half4v w = {(_Float16)p0, (_Float16)p1, (_Float16)p2, (_Float16)p3};
      // Ps[i][j]: i = nt*16+c, j = wave*16 + q4*4 + 0..3
      *(half4v*)&Ps[(nt * 16 + c) * 72 + wave * 16 + q4 * 4] = w;
    }
    __syncthreads();   // Ps visible (Ks fully consumed above)

    // ---- O += P·V : wave owns 32 i-rows; V frags shared across subs ----
    half8 vb0[4], vb1[4];
#pragma unroll
    for (int dt = 0; dt < 4; ++dt) {
      vb0[dt] = *(const half8*)&Vt[0][(dt * 16 + c) * 32 + (q4 ^ rsw) * 8];
      vb1[dt] = *(const half8*)&Vt[1][(dt * 16 + c) * 32 + (q4 ^ rsw) * 8];
    }
#pragma unroll
    for (int sub = 0; sub < 2; ++sub) {
      half8 pa0 = *(const half8*)&Ps[(wave * 32 + sub * 16 + c) * 72 + q4 * 8];
      half8 pa1 = *(const half8*)&Ps[(wave * 32 + sub * 16 + c) * 72 + 32 + q4 * 8];
#pragma unroll
      for (int dt = 0; dt < 4; ++dt) {
        o_acc[sub][dt] = __builtin_amdgcn_mfma_f32_16x16x32_f16(
            pa0, vb0[dt], o_acc[sub][dt], 0, 0, 0);
        o_acc[sub][dt] = __builtin_amdgcn_mfma_f32_16x16x32_f16(
            pa1, vb1[dt], o_acc[sub][dt], 0, 0, 0);
      }
    }
  }

  // ---- l: reduce over q4 (same i, disjoint j), then across waves ----
#pragma unroll
  for (int nt = 0; nt < 8; ++nt) {
    lp[nt] += __shfl_xor(lp[nt], 16);
    lp[nt] += __shfl_xor(lp[nt], 32);
  }
  if (q4 == 0)
#pragma unroll
    for (int nt = 0; nt < 8; ++nt) lred[wave][nt * 16 + c] = lp[nt];
  __syncthreads();
  if (tid < 128)
    lfull[tid] = lred[0][tid] + lred[1][tid] + lred[2][tid] + lred[3][tid];
  __syncthreads();

  // ---- Finalize: O[i][d] /= l[i], store fp16 ctx[token][h*64+d] ----
#pragma unroll
  for (int sub = 0; sub < 2; ++sub)
#pragma unroll
    for (int r = 0; r < 4; ++r) {
      int i = wave * 32 + sub * 16 + q4 * 4 + r;
      float inv = 1.0f / lfull[i];
      size_t row = (size_t)b * SEQ + qrow0 + i;
#pragma unroll
      for (int dt = 0; dt < 4; ++dt)
        ((_Float16*)ctx)[row * DIM + h * HD + dt * 16 + c] =
            (_Float16)(o_acc[sub][dt][r] * inv);
    }
}

// ---------------------------------------------------------------------------
extern "C" void kernel_launch(void* const* d_in, const int* in_sizes, int n_in,
                              void* d_out, int out_size, void* d_ws, size_t ws_size,
                              hipStream_t stream) {
  const float* x    = (const float*)d_in[0];
  const float* Wqkv = (const float*)d_in[1];
  const float* Wout = (const float*)d_in[2];
  const float* bout = (const float*)d_in[3];
  float* out = (float*)d_out;

  // workspace (fp16 as u16), ~92 MB total
  u16* xh   = (u16*)d_ws;                              // [8192,1024]
  u16* Wqt  = xh  + (size_t)ROWS * DIM;                // [3072,1024]
  u16* Wot  = Wqt + (size_t)QKV_N * DIM;               // [1024,1024]
  u16* Qg   = Wot + (size_t)DIM * DIM;                 // [64,2048,64] (×ATT_C)
  u16* Kg   = Qg  + (size_t)BATCH * HEADS * SEQ * HD;  // [64,2048,64]
  u16* VtG  = Kg  + (size_t)BATCH * HEADS * SEQ * HD;  // [64,64,2048]
  u16* ctxh = VtG + (size_t)BATCH * HEADS * HD * SEQ;  // [8192,1024]

  conv_x<<<ROWS * DIM / 4 / 256, 256, 0, stream>>>(x, xh);
  conv_w<<<dim3(QKV_N / 64, DIM / 64), 256, 0, stream>>>(Wqkv, Wqt, DIM, QKV_N);
  conv_w<<<dim3(DIM / 64, DIM / 64), 256, 0, stream>>>(Wout, Wot, DIM, DIM);

  // 1) qkv = x @ Wqkv (fp16 MFMA), repack -> Qg (×ATT_C) / Kg / VtG
  gemm_bt<1><<<dim3(QKV_N / 128, ROWS / 128), 256, 0, stream>>>(
      xh, Wqt, nullptr, nullptr, Qg, Kg, VtG, ROWS, QKV_N, DIM);

  // 2) attention -> ctxh (fp16), Q-tile 128, 3 blocks/CU (no spill)
  attn_mfma<<<dim3(1024), 256, 0, stream>>>(Qg, Kg, VtG, ctxh);

  // 3) out = ctx @ Wout + bout (fp32)
  gemm_bt<0><<<dim3(DIM / 128, ROWS / 128), 256, 0, stream>>>(
      ctxh, Wot, bout, out, nullptr, nullptr, nullptr, ROWS, DIM, DIM);
}

// Round 9
// 305.801 us; speedup vs baseline: 1.1739x; 1.0242x over previous
//
#include <hip/hip_runtime.h>
#include <hip/hip_bf16.h>

// Problem constants
#define BATCH 4
#define SEQ   2048
#define DIM   1024
#define HEADS 16
#define HD    64
#define ROWS  (BATCH * SEQ)   // 8192
#define QKV_N (3 * DIM)       // 3072
#define ATT_C 0.18033688011f  // 0.125 * log2(e)  (folded into Q at gemm1)

typedef unsigned short u16;
typedef _Float16 half8 __attribute__((ext_vector_type(8)));   // 8 f16 (4 VGPRs)
typedef _Float16 half4v __attribute__((ext_vector_type(4)));  // 8B packed store
typedef float f32x4 __attribute__((ext_vector_type(4)));      // MFMA accumulator

// async global->LDS, 16B per lane; LDS dest = wave-uniform base + lane*16
__device__ __forceinline__ void gload_lds16(const u16* g, u16* l) {
  typedef const __attribute__((address_space(1))) unsigned int* gp_t;
  typedef __attribute__((address_space(3))) unsigned int* lp_t;
  __builtin_amdgcn_global_load_lds((gp_t)(const void*)g, (lp_t)(void*)l, 16, 0, 0);
}

// ---------------------------------------------------------------------------
// conv_x: x fp32 [8192,1024] -> xh fp16 [8192,1024]
// ---------------------------------------------------------------------------
__global__ __launch_bounds__(256) void conv_x(const float* __restrict__ x,
                                              u16* __restrict__ xh) {
  int i = blockIdx.x * 256 + threadIdx.x;
  float4 v = ((const float4*)x)[i];
  half4v h = {(_Float16)v.x, (_Float16)v.y, (_Float16)v.z, (_Float16)v.w};
  *(half4v*)&xh[(size_t)i * 4] = h;
}

// ---------------------------------------------------------------------------
// conv_w: W fp32 [K,N] -> Wt fp16 [N,K] transposed
// ---------------------------------------------------------------------------
__global__ __launch_bounds__(256) void conv_w(const float* __restrict__ W,
                                              u16* __restrict__ Wt,
                                              int K, int N) {
  __shared__ float T[64][65];
  const int tid = threadIdx.x;
  const int k0 = blockIdx.y * 64, n0 = blockIdx.x * 64;
#pragma unroll
  for (int j = 0; j < 4; ++j) {
    int k = j * 16 + (tid >> 4), n4 = (tid & 15) * 4;
    float4 v = *(const float4*)(W + (size_t)(k0 + k) * N + n0 + n4);
    T[k][n4 + 0] = v.x; T[k][n4 + 1] = v.y; T[k][n4 + 2] = v.z; T[k][n4 + 3] = v.w;
  }
  __syncthreads();
#pragma unroll
  for (int j = 0; j < 4; ++j) {
    int n = j * 16 + (tid >> 4), k4 = (tid & 15) * 4;
    half4v w = {(_Float16)T[k4 + 0][n], (_Float16)T[k4 + 1][n],
                (_Float16)T[k4 + 2][n], (_Float16)T[k4 + 3][n]};
    *(half4v*)&Wt[(size_t)(n0 + n) * K + k0 + k4] = w;
  }
}

// ---------------------------------------------------------------------------
// m97-style fp16 MFMA GEMM: C = A[M,K] @ Bt[N,K]^T, fp32 accum.
// MODE 0: fp32 out + bias (out-projection).
// MODE 1: repack epilogue -> Qg (pre-scaled by ATT_C) / Kg / VtG, fp16.
// ---------------------------------------------------------------------------
template <int MODE>
__global__ __launch_bounds__(256) void gemm_bt(
    const u16* __restrict__ A, const u16* __restrict__ Bt,
    const float* __restrict__ bias, void* __restrict__ Cv,
    u16* __restrict__ Qg, u16* __restrict__ Kg, u16* __restrict__ VtG,
    int M, int N, int K) {
  __shared__ u16 As[128 * 32];
  __shared__ u16 Bs[128 * 32];

  const int tid = threadIdx.x;
  const int wave = tid >> 6, lane = tid & 63;
  const int q4 = lane >> 4, c = lane & 15;
  const int wm = wave >> 1, wn = wave & 1;
  const int row0 = blockIdx.y * 128, col0 = blockIdx.x * 128;
  const int rr = lane >> 2, seg = lane & 3;

  f32x4 acc[4][4];
#pragma unroll
  for (int mi = 0; mi < 4; ++mi)
#pragma unroll
    for (int ni = 0; ni < 4; ++ni) acc[mi][ni] = (f32x4){0.f, 0.f, 0.f, 0.f};

  for (int k0 = 0; k0 < K; k0 += 32) {
#pragma unroll
    for (int i = 0; i < 2; ++i) {
      int chunk = wave * 2 + i;
      gload_lds16(A + (size_t)(row0 + chunk * 16 + rr) * K + k0 + seg * 8,
                  &As[chunk * 512]);
      gload_lds16(Bt + (size_t)(col0 + chunk * 16 + rr) * K + k0 + seg * 8,
                  &Bs[chunk * 512]);
    }
    __syncthreads();

    half8 af[4], bf[4];
#pragma unroll
    for (int mi = 0; mi < 4; ++mi)
      af[mi] = *(const half8*)&As[(wm * 64 + mi * 16 + c) * 32 + q4 * 8];
#pragma unroll
    for (int ni = 0; ni < 4; ++ni)
      bf[ni] = *(const half8*)&Bs[(wn * 64 + ni * 16 + c) * 32 + q4 * 8];
#pragma unroll
    for (int mi = 0; mi < 4; ++mi)
#pragma unroll
      for (int ni = 0; ni < 4; ++ni)
        acc[mi][ni] = __builtin_amdgcn_mfma_f32_16x16x32_f16(
            af[mi], bf[ni], acc[mi][ni], 0, 0, 0);
    __syncthreads();
  }

#pragma unroll
  for (int mi = 0; mi < 4; ++mi)
#pragma unroll
    for (int ni = 0; ni < 4; ++ni) {
      int colg = col0 + wn * 64 + ni * 16 + c;
      if (MODE == 0) {
        float bv = bias[colg];
#pragma unroll
        for (int r = 0; r < 4; ++r) {
          int rowg = row0 + wm * 64 + mi * 16 + q4 * 4 + r;
          ((float*)Cv)[(size_t)rowg * N + colg] = acc[mi][ni][r] + bv;
        }
      } else {
        int rowg0 = row0 + wm * 64 + mi * 16 + q4 * 4;   // 4 consecutive tokens
        int b  = rowg0 >> 11;
        int which = colg >> 10;            // 0=Q 1=K 2=V (uniform per block)
        int rem = colg & 1023;
        int hh = rem >> 6, d = rem & 63;
        size_t bh = (size_t)(b * HEADS + hh);
        if (which == 2) {
          int i0 = rowg0 & 2047;
          half4v pv = {(_Float16)acc[mi][ni][0], (_Float16)acc[mi][ni][1],
                       (_Float16)acc[mi][ni][2], (_Float16)acc[mi][ni][3]};
          *(half4v*)&VtG[(bh * HD + d) * SEQ + i0] = pv;
        } else {
          u16* dst = (which == 0) ? Qg : Kg;
          float sc = (which == 0) ? ATT_C : 1.0f;   // fold softmax scale into Q
#pragma unroll
          for (int r = 0; r < 4; ++r) {
            int i = (rowg0 + r) & 2047;
            ((_Float16*)dst)[(bh * SEQ + i) * HD + d] =
                (_Float16)(acc[mi][ni][r] * sc);
          }
        }
      }
    }
}

// ---------------------------------------------------------------------------
// Flash attention fp16, Q-tile=128, j-tile=64, no-max softmax.
// S^T = K·(Q*c)^T; Q fragments loaded DIRECTLY global->registers.
// DOUBLE-BUFFERED K/V staging: next j-tile's global_load_lds issued before
// computing on the current buffer, so load latency overlaps S-compute and
// the compiler's vmcnt(0) drain lands on the (already required) Ps barrier.
// 2 barriers/iter (was 3). LDS total 53,760 B -> 3 blocks/CU.
// __launch_bounds__(256,3): reg budget ~170; (256,4)=128 spilled (R7:
// FETCH 356 MB of scratch traffic). Do not raise.
// Grid: 1-D 1024, bh = L&63 -> same-head blocks land on one XCD (%8).
// ---------------------------------------------------------------------------
__global__ __launch_bounds__(256, 3) void attn_mfma(
    const u16* __restrict__ Qg, const u16* __restrict__ Kg,
    const u16* __restrict__ VtG, u16* __restrict__ ctx) {
  const int L  = blockIdx.x;       // 0..1023
  const int bh = L & 63;
  const int b  = bh >> 4, h = bh & 15;
  const int qt = L >> 6;           // 0..15

  __shared__ u16 Ks[2][2][64 * 32];   // [buf][k-half] 16 KB
  __shared__ u16 Vt[2][2][64 * 32];   // 16 KB
  __shared__ u16 Ps[128 * 72];        // 18.4 KB
  __shared__ float lred[4][128];      // 2 KB
  __shared__ float lfull[128];        // 0.5 KB

  const int tid  = threadIdx.x;
  const int wave = tid >> 6;
  const int lane = tid & 63;
  const int q4   = lane >> 4;
  const int c    = lane & 15;
  const int rr   = lane >> 2, seg = lane & 3;
  const int sseg = seg ^ (rr & 3);       // staging-side XOR swizzle
  const int rsw  = (c & 3);              // read-side counter-swizzle

  const size_t bhb = (size_t)bh;
  const int qrow0 = qt * 128;

  // ---- Initial K/V prefetch (j0 = 0) into buffer 0 ----
#pragma unroll
  for (int half = 0; half < 2; ++half) {
    gload_lds16(Kg + (bhb * SEQ + wave * 16 + rr) * HD + half * 32 + sseg * 8,
                &Ks[0][half][wave * 16 * 32]);
    gload_lds16(VtG + (bhb * HD + wave * 16 + rr) * SEQ + half * 32 + sseg * 8,
                &Vt[0][half][wave * 16 * 32]);
  }

  // ---- Q fragments: direct global->register (one-time, loop-invariant) ----
  // B-operand layout: B[n = i = nt*16+c][k = d = half*32 + q4*8 + 0..7]
  half8 qf[8][2];
#pragma unroll
  for (int nt = 0; nt < 8; ++nt)
#pragma unroll
    for (int half = 0; half < 2; ++half)
      qf[nt][half] = *(const half8*)&Qg[(bhb * SEQ + qrow0 + nt * 16 + c) * HD
                                        + half * 32 + q4 * 8];

  f32x4 o_acc[2][4];
#pragma unroll
  for (int sub = 0; sub < 2; ++sub)
#pragma unroll
    for (int dt = 0; dt < 4; ++dt) o_acc[sub][dt] = (f32x4){0.f, 0.f, 0.f, 0.f};
  float lp[8] = {0.f, 0.f, 0.f, 0.f, 0.f, 0.f, 0.f, 0.f};

  __syncthreads();   // initial prefetch drained

  for (int j0 = 0; j0 < SEQ; j0 += 64) {
    const int cb = (j0 >> 6) & 1;

    // ---- Prefetch next j-tile into the other buffer (overlaps S-compute) ----
    if (j0 + 64 < SEQ) {
      const int jn = j0 + 64, nb = cb ^ 1;
#pragma unroll
      for (int half = 0; half < 2; ++half) {
        gload_lds16(Kg + (bhb * SEQ + jn + wave * 16 + rr) * HD
                        + half * 32 + sseg * 8,
                    &Ks[nb][half][wave * 16 * 32]);
        gload_lds16(VtG + (bhb * HD + wave * 16 + rr) * SEQ + jn
                        + half * 32 + sseg * 8,
                    &Vt[nb][half][wave * 16 * 32]);
      }
    }

    // ---- St = K·Q^T : wave owns 16 j-rows; softmax fused per nt ----
    half8 af0 = *(const half8*)&Ks[cb][0][(wave * 16 + c) * 32 + (q4 ^ rsw) * 8];
    half8 af1 = *(const half8*)&Ks[cb][1][(wave * 16 + c) * 32 + (q4 ^ rsw) * 8];
#pragma unroll
    for (int nt = 0; nt < 8; ++nt) {
      f32x4 st = (f32x4){0.f, 0.f, 0.f, 0.f};
      st = __builtin_amdgcn_mfma_f32_16x16x32_f16(af0, qf[nt][0], st, 0, 0, 0);
      st = __builtin_amdgcn_mfma_f32_16x16x32_f16(af1, qf[nt][1], st, 0, 0, 0);
      float p0 = __builtin_amdgcn_exp2f(st[0]);
      float p1 = __builtin_amdgcn_exp2f(st[1]);
      float p2 = __builtin_amdgcn_exp2f(st[2]);
      float p3 = __builtin_amdgcn_exp2f(st[3]);
      lp[nt] += (p0 + p1) + (p2 + p3);
      half4v w = {(_Float16)p0, (_Float16)p1, (_Float16)p2, (_Float16)p3};
      // Ps[i][j]: i = nt*16+c, j = wave*16 + q4*4 + 0..3
      *(half4v*)&Ps[(nt * 16 + c) * 72 + wave * 16 + q4 * 4] = w;
    }
    __syncthreads();   // Ps visible; prefetch vmcnt drained here (overlapped)

    // ---- O += P·V : wave owns 32 i-rows; V frags shared across subs ----
    half8 vb0[4], vb1[4];
#pragma unroll
    for (int dt = 0; dt < 4; ++dt) {
      vb0[dt] = *(const half8*)&Vt[cb][0][(dt * 16 + c) * 32 + (q4 ^ rsw) * 8];
      vb1[dt] = *(const half8*)&Vt[cb][1][(dt * 16 + c) * 32 + (q4 ^ rsw) * 8];
    }
#pragma unroll
    for (int sub = 0; sub < 2; ++sub) {
      half8 pa0 = *(const half8*)&Ps[(wave * 32 + sub * 16 + c) * 72 + q4 * 8];
      half8 pa1 = *(const half8*)&Ps[(wave * 32 + sub * 16 + c) * 72 + 32 + q4 * 8];
#pragma unroll
      for (int dt = 0; dt < 4; ++dt) {
        o_acc[sub][dt] = __builtin_amdgcn_mfma_f32_16x16x32_f16(
            pa0, vb0[dt], o_acc[sub][dt], 0, 0, 0);
        o_acc[sub][dt] = __builtin_amdgcn_mfma_f32_16x16x32_f16(
            pa1, vb1[dt], o_acc[sub][dt], 0, 0, 0);
      }
    }
    __syncthreads();   // Ps reads done (next iter overwrites); cb^1 staged
  }

  // ---- l: reduce over q4 (same i, disjoint j), then across waves ----
#pragma unroll
  for (int nt = 0; nt < 8; ++nt) {
    lp[nt] += __shfl_xor(lp[nt], 16);
    lp[nt] += __shfl_xor(lp[nt], 32);
  }
  if (q4 == 0)
#pragma unroll
    for (int nt = 0; nt < 8; ++nt) lred[wave][nt * 16 + c] = lp[nt];
  __syncthreads();
  if (tid < 128)
    lfull[tid] = lred[0][tid] + lred[1][tid] + lred[2][tid] + lred[3][tid];
  __syncthreads();

  // ---- Finalize: O[i][d] /= l[i], store fp16 ctx[token][h*64+d] ----
#pragma unroll
  for (int sub = 0; sub < 2; ++sub)
#pragma unroll
    for (int r = 0; r < 4; ++r) {
      int i = wave * 32 + sub * 16 + q4 * 4 + r;
      float inv = 1.0f / lfull[i];
      size_t row = (size_t)b * SEQ + qrow0 + i;
#pragma unroll
      for (int dt = 0; dt < 4; ++dt)
        ((_Float16*)ctx)[row * DIM + h * HD + dt * 16 + c] =
            (_Float16)(o_acc[sub][dt][r] * inv);
    }
}

// ---------------------------------------------------------------------------
extern "C" void kernel_launch(void* const* d_in, const int* in_sizes, int n_in,
                              void* d_out, int out_size, void* d_ws, size_t ws_size,
                              hipStream_t stream) {
  const float* x    = (const float*)d_in[0];
  const float* Wqkv = (const float*)d_in[1];
  const float* Wout = (const float*)d_in[2];
  const float* bout = (const float*)d_in[3];
  float* out = (float*)d_out;

  // workspace (fp16 as u16), ~92 MB total
  u16* xh   = (u16*)d_ws;                              // [8192,1024]
  u16* Wqt  = xh  + (size_t)ROWS * DIM;                // [3072,1024]
  u16* Wot  = Wqt + (size_t)QKV_N * DIM;               // [1024,1024]
  u16* Qg   = Wot + (size_t)DIM * DIM;                 // [64,2048,64] (×ATT_C)
  u16* Kg   = Qg  + (size_t)BATCH * HEADS * SEQ * HD;  // [64,2048,64]
  u16* VtG  = Kg  + (size_t)BATCH * HEADS * SEQ * HD;  // [64,64,2048]
  u16* ctxh = VtG + (size_t)BATCH * HEADS * HD * SEQ;  // [8192,1024]

  conv_x<<<ROWS * DIM / 4 / 256, 256, 0, stream>>>(x, xh);
  conv_w<<<dim3(QKV_N / 64, DIM / 64), 256, 0, stream>>>(Wqkv, Wqt, DIM, QKV_N);
  conv_w<<<dim3(DIM / 64, DIM / 64), 256, 0, stream>>>(Wout, Wot, DIM, DIM);

  // 1) qkv = x @ Wqkv (fp16 MFMA), repack -> Qg (×ATT_C) / Kg / VtG
  gemm_bt<1><<<dim3(QKV_N / 128, ROWS / 128), 256, 0, stream>>>(
      xh, Wqt, nullptr, nullptr, Qg, Kg, VtG, ROWS, QKV_N, DIM);

  // 2) attention -> ctxh (fp16), double-buffered K/V prefetch
  attn_mfma<<<dim3(1024), 256, 0, stream>>>(Qg, Kg, VtG, ctxh);

  // 3) out = ctx @ Wout + bout (fp32)
  gemm_bt<0><<<dim3(DIM / 128, ROWS / 128), 256, 0, stream>>>(
      ctxh, Wot, bout, out, nullptr, nullptr, nullptr, ROWS, DIM, DIM);
}

// Round 10
// 296.191 us; speedup vs baseline: 1.2120x; 1.0324x over previous
//
#include <hip/hip_runtime.h>
#include <hip/hip_bf16.h>

// Problem constants
#define BATCH 4
#define SEQ   2048
#define DIM   1024
#define HEADS 16
#define HD    64
#define ROWS  (BATCH * SEQ)   // 8192
#define QKV_N (3 * DIM)       // 3072
#define ATT_C 0.18033688011f  // 0.125 * log2(e)  (folded into Q at gemm1)

typedef unsigned short u16;
typedef _Float16 half8 __attribute__((ext_vector_type(8)));   // 8 f16 (4 VGPRs)
typedef _Float16 half4v __attribute__((ext_vector_type(4)));  // 8B packed store
typedef float f32x4 __attribute__((ext_vector_type(4)));      // MFMA accumulator

// async global->LDS, 16B per lane; LDS dest = wave-uniform base + lane*16
__device__ __forceinline__ void gload_lds16(const u16* g, u16* l) {
  typedef const __attribute__((address_space(1))) unsigned int* gp_t;
  typedef __attribute__((address_space(3))) unsigned int* lp_t;
  __builtin_amdgcn_global_load_lds((gp_t)(const void*)g, (lp_t)(void*)l, 16, 0, 0);
}

// ---------------------------------------------------------------------------
// conv_x: x fp32 [8192,1024] -> xh fp16 [8192,1024]
// ---------------------------------------------------------------------------
__global__ __launch_bounds__(256) void conv_x(const float* __restrict__ x,
                                              u16* __restrict__ xh) {
  int i = blockIdx.x * 256 + threadIdx.x;
  float4 v = ((const float4*)x)[i];
  half4v h = {(_Float16)v.x, (_Float16)v.y, (_Float16)v.z, (_Float16)v.w};
  *(half4v*)&xh[(size_t)i * 4] = h;
}

// ---------------------------------------------------------------------------
// conv_w: W fp32 [K,N] -> Wt fp16 [N,K] transposed
// ---------------------------------------------------------------------------
__global__ __launch_bounds__(256) void conv_w(const float* __restrict__ W,
                                              u16* __restrict__ Wt,
                                              int K, int N) {
  __shared__ float T[64][65];
  const int tid = threadIdx.x;
  const int k0 = blockIdx.y * 64, n0 = blockIdx.x * 64;
#pragma unroll
  for (int j = 0; j < 4; ++j) {
    int k = j * 16 + (tid >> 4), n4 = (tid & 15) * 4;
    float4 v = *(const float4*)(W + (size_t)(k0 + k) * N + n0 + n4);
    T[k][n4 + 0] = v.x; T[k][n4 + 1] = v.y; T[k][n4 + 2] = v.z; T[k][n4 + 3] = v.w;
  }
  __syncthreads();
#pragma unroll
  for (int j = 0; j < 4; ++j) {
    int n = j * 16 + (tid >> 4), k4 = (tid & 15) * 4;
    half4v w = {(_Float16)T[k4 + 0][n], (_Float16)T[k4 + 1][n],
                (_Float16)T[k4 + 2][n], (_Float16)T[k4 + 3][n]};
    *(half4v*)&Wt[(size_t)(n0 + n) * K + k0 + k4] = w;
  }
}

// ---------------------------------------------------------------------------
// m97-style fp16 MFMA GEMM: C = A[M,K] @ Bt[N,K]^T, fp32 accum.
// MODE 0: fp32 out + bias (out-projection).
// MODE 1: repack epilogue -> Qg (pre-scaled by ATT_C) / Kg / VtG, fp16.
// ---------------------------------------------------------------------------
template <int MODE>
__global__ __launch_bounds__(256) void gemm_bt(
    const u16* __restrict__ A, const u16* __restrict__ Bt,
    const float* __restrict__ bias, void* __restrict__ Cv,
    u16* __restrict__ Qg, u16* __restrict__ Kg, u16* __restrict__ VtG,
    int M, int N, int K) {
  __shared__ u16 As[128 * 32];
  __shared__ u16 Bs[128 * 32];

  const int tid = threadIdx.x;
  const int wave = tid >> 6, lane = tid & 63;
  const int q4 = lane >> 4, c = lane & 15;
  const int wm = wave >> 1, wn = wave & 1;
  const int row0 = blockIdx.y * 128, col0 = blockIdx.x * 128;
  const int rr = lane >> 2, seg = lane & 3;

  f32x4 acc[4][4];
#pragma unroll
  for (int mi = 0; mi < 4; ++mi)
#pragma unroll
    for (int ni = 0; ni < 4; ++ni) acc[mi][ni] = (f32x4){0.f, 0.f, 0.f, 0.f};

  for (int k0 = 0; k0 < K; k0 += 32) {
#pragma unroll
    for (int i = 0; i < 2; ++i) {
      int chunk = wave * 2 + i;
      gload_lds16(A + (size_t)(row0 + chunk * 16 + rr) * K + k0 + seg * 8,
                  &As[chunk * 512]);
      gload_lds16(Bt + (size_t)(col0 + chunk * 16 + rr) * K + k0 + seg * 8,
                  &Bs[chunk * 512]);
    }
    __syncthreads();

    half8 af[4], bf[4];
#pragma unroll
    for (int mi = 0; mi < 4; ++mi)
      af[mi] = *(const half8*)&As[(wm * 64 + mi * 16 + c) * 32 + q4 * 8];
#pragma unroll
    for (int ni = 0; ni < 4; ++ni)
      bf[ni] = *(const half8*)&Bs[(wn * 64 + ni * 16 + c) * 32 + q4 * 8];
#pragma unroll
    for (int mi = 0; mi < 4; ++mi)
#pragma unroll
      for (int ni = 0; ni < 4; ++ni)
        acc[mi][ni] = __builtin_amdgcn_mfma_f32_16x16x32_f16(
            af[mi], bf[ni], acc[mi][ni], 0, 0, 0);
    __syncthreads();
  }

#pragma unroll
  for (int mi = 0; mi < 4; ++mi)
#pragma unroll
    for (int ni = 0; ni < 4; ++ni) {
      int colg = col0 + wn * 64 + ni * 16 + c;
      if (MODE == 0) {
        float bv = bias[colg];
#pragma unroll
        for (int r = 0; r < 4; ++r) {
          int rowg = row0 + wm * 64 + mi * 16 + q4 * 4 + r;
          ((float*)Cv)[(size_t)rowg * N + colg] = acc[mi][ni][r] + bv;
        }
      } else {
        int rowg0 = row0 + wm * 64 + mi * 16 + q4 * 4;   // 4 consecutive tokens
        int b  = rowg0 >> 11;
        int which = colg >> 10;            // 0=Q 1=K 2=V (uniform per block)
        int rem = colg & 1023;
        int hh = rem >> 6, d = rem & 63;
        size_t bh = (size_t)(b * HEADS + hh);
        if (which == 2) {
          int i0 = rowg0 & 2047;
          half4v pv = {(_Float16)acc[mi][ni][0], (_Float16)acc[mi][ni][1],
                       (_Float16)acc[mi][ni][2], (_Float16)acc[mi][ni][3]};
          *(half4v*)&VtG[(bh * HD + d) * SEQ + i0] = pv;
        } else {
          u16* dst = (which == 0) ? Qg : Kg;
          float sc = (which == 0) ? ATT_C : 1.0f;   // fold softmax scale into Q
#pragma unroll
          for (int r = 0; r < 4; ++r) {
            int i = (rowg0 + r) & 2047;
            ((_Float16*)dst)[(bh * SEQ + i) * HD + d] =
                (_Float16)(acc[mi][ni][r] * sc);
          }
        }
      }
    }
}

// ---------------------------------------------------------------------------
// Flash attention fp16: 512 threads (8 waves), Q-tile=128, j-tile=128,
// no-max softmax, single-buffered staging (dbuf was neutral: vmcnt(0)
// drains at barriers regardless — R9). Work per barrier-triple doubled
// vs R8 (16 iters, 32 MFMA/wave/iter). LDS ~73 KB -> 2 blocks/CU =
// 16 waves/CU, grid 1024 at 2/CU = exactly 2 full rounds (no tail).
// St = K·(Q*c)^T: wave owns 16 j-rows; PV: wave owns 16 i-rows.
// __launch_bounds__(512,4): 128-VGPR budget; est. demand ~118 (qf 64 +
// o_acc 16 + temps). R7 lesson: spill shows up as FETCH explosion.
// Grid: 1-D 1024, bh = L&63 -> same-head blocks land on one XCD (%8).
// ---------------------------------------------------------------------------
#define PSTR 140

__global__ __launch_bounds__(512, 4) void attn_mfma(
    const u16* __restrict__ Qg, const u16* __restrict__ Kg,
    const u16* __restrict__ VtG, u16* __restrict__ ctx) {
  const int L  = blockIdx.x;       // 0..1023
  const int bh = L & 63;
  const int b  = bh >> 4, h = bh & 15;
  const int qt = L >> 6;           // 0..7? no: 0..15

  __shared__ u16 Ks[2][128 * 32];     // [d-half][j-row] 16 KB
  __shared__ u16 Vt[4][64 * 32];      // [j-quarter][d-row] 16 KB
  __shared__ u16 Ps[128 * PSTR];      // 35.8 KB, stride 140 (bank-checked)
  __shared__ float lred[8][128];      // 4 KB
  __shared__ float lfull[128];        // 0.5 KB

  const int tid  = threadIdx.x;
  const int wave = tid >> 6;          // 0..7
  const int lane = tid & 63;
  const int q4   = lane >> 4;
  const int c    = lane & 15;
  const int rr   = lane >> 2, seg = lane & 3;
  const int sseg = seg ^ (rr & 3);    // staging-side XOR swizzle
  const int rsw  = (c & 3);           // read-side counter-swizzle

  const size_t bhb = (size_t)bh;
  const int qrow0 = qt * 128;

  // ---- Q fragments: direct global->register (one-time, loop-invariant) ----
  // B-operand: B[n = i = nt*16+c][k = d = kh*32 + q4*8 + 0..7]
  half8 qf[8][2];
#pragma unroll
  for (int nt = 0; nt < 8; ++nt)
#pragma unroll
    for (int kh = 0; kh < 2; ++kh)
      qf[nt][kh] = *(const half8*)&Qg[(bhb * SEQ + qrow0 + nt * 16 + c) * HD
                                      + kh * 32 + q4 * 8];

  f32x4 o_acc[4];
#pragma unroll
  for (int dt = 0; dt < 4; ++dt) o_acc[dt] = (f32x4){0.f, 0.f, 0.f, 0.f};
  float lp[8] = {0.f, 0.f, 0.f, 0.f, 0.f, 0.f, 0.f, 0.f};

  for (int j0 = 0; j0 < SEQ; j0 += 128) {
    __syncthreads();   // prior iter's Ks/Vt/Ps reads complete

    // ---- Stage K (128 j-rows x 64 d) and V^T (64 d-rows x 128 j) ----
#pragma unroll
    for (int i = 0; i < 2; ++i) {
      int chunk = wave * 2 + i;            // 0..15
      // K: kh = chunk>>3 (d-half), jr = chunk&7 (16-j-row group)
      int kh = chunk >> 3, jr = chunk & 7;
      gload_lds16(Kg + (bhb * SEQ + j0 + jr * 16 + rr) * HD + kh * 32 + sseg * 8,
                  &Ks[kh][jr * 16 * 32]);
      // V: q = chunk>>2 (j-quarter), d16 = chunk&3 (16-d-row group)
      int q = chunk >> 2, d16 = chunk & 3;
      gload_lds16(VtG + (bhb * HD + d16 * 16 + rr) * SEQ + j0 + q * 32 + sseg * 8,
                  &Vt[q][d16 * 16 * 32]);
    }
    __syncthreads();   // staging done (vmcnt drained)

    // ---- St = K·Q^T : wave owns 16 j-rows (j = j0 + wave*16 + ...) ----
    half8 af0 = *(const half8*)&Ks[0][(wave * 16 + c) * 32 + (q4 ^ rsw) * 8];
    half8 af1 = *(const half8*)&Ks[1][(wave * 16 + c) * 32 + (q4 ^ rsw) * 8];
#pragma unroll
    for (int nt = 0; nt < 8; ++nt) {
      f32x4 st = (f32x4){0.f, 0.f, 0.f, 0.f};
      st = __builtin_amdgcn_mfma_f32_16x16x32_f16(af0, qf[nt][0], st, 0, 0, 0);
      st = __builtin_amdgcn_mfma_f32_16x16x32_f16(af1, qf[nt][1], st, 0, 0, 0);
      float p0 = __builtin_amdgcn_exp2f(st[0]);
      float p1 = __builtin_amdgcn_exp2f(st[1]);
      float p2 = __builtin_amdgcn_exp2f(st[2]);
      float p3 = __builtin_amdgcn_exp2f(st[3]);
      lp[nt] += (p0 + p1) + (p2 + p3);
      half4v w = {(_Float16)p0, (_Float16)p1, (_Float16)p2, (_Float16)p3};
      // Ps[i][j-local]: i = nt*16+c, j = wave*16 + q4*4 + 0..3
      *(half4v*)&Ps[(nt * 16 + c) * PSTR + wave * 16 + q4 * 4] = w;
    }
    __syncthreads();   // all waves' Ps strips visible

    // ---- O += P·V : wave owns 16 i-rows (i = wave*16 + ...) ----
#pragma unroll
    for (int kc = 0; kc < 4; ++kc) {
      half8 pa = *(const half8*)&Ps[(wave * 16 + c) * PSTR + kc * 32 + q4 * 8];
#pragma unroll
      for (int dt = 0; dt < 4; ++dt) {
        half8 vb = *(const half8*)&Vt[kc][(dt * 16 + c) * 32 + (q4 ^ rsw) * 8];
        o_acc[dt] = __builtin_amdgcn_mfma_f32_16x16x32_f16(
            pa, vb, o_acc[dt], 0, 0, 0);
      }
    }
  }

  // ---- l: reduce over q4 (same i, disjoint j), then across 8 waves ----
#pragma unroll
  for (int nt = 0; nt < 8; ++nt) {
    lp[nt] += __shfl_xor(lp[nt], 16);
    lp[nt] += __shfl_xor(lp[nt], 32);
  }
  if (q4 == 0)
#pragma unroll
    for (int nt = 0; nt < 8; ++nt) lred[wave][nt * 16 + c] = lp[nt];
  __syncthreads();
  if (tid < 128) {
    float s = 0.f;
#pragma unroll
    for (int w = 0; w < 8; ++w) s += lred[w][tid];
    lfull[tid] = s;
  }
  __syncthreads();

  // ---- Finalize: O[i][d] /= l[i], store fp16 ctx[token][h*64+d] ----
#pragma unroll
  for (int r = 0; r < 4; ++r) {
    int i = wave * 16 + q4 * 4 + r;
    float inv = 1.0f / lfull[i];
    size_t row = (size_t)b * SEQ + qrow0 + i;
#pragma unroll
    for (int dt = 0; dt < 4; ++dt)
      ((_Float16*)ctx)[row * DIM + h * HD + dt * 16 + c] =
          (_Float16)(o_acc[dt][r] * inv);
  }
}

// ---------------------------------------------------------------------------
extern "C" void kernel_launch(void* const* d_in, const int* in_sizes, int n_in,
                              void* d_out, int out_size, void* d_ws, size_t ws_size,
                              hipStream_t stream) {
  const float* x    = (const float*)d_in[0];
  const float* Wqkv = (const float*)d_in[1];
  const float* Wout = (const float*)d_in[2];
  const float* bout = (const float*)d_in[3];
  float* out = (float*)d_out;

  // workspace (fp16 as u16), ~92 MB total
  u16* xh   = (u16*)d_ws;                              // [8192,1024]
  u16* Wqt  = xh  + (size_t)ROWS * DIM;                // [3072,1024]
  u16* Wot  = Wqt + (size_t)QKV_N * DIM;               // [1024,1024]
  u16* Qg   = Wot + (size_t)DIM * DIM;                 // [64,2048,64] (×ATT_C)
  u16* Kg   = Qg  + (size_t)BATCH * HEADS * SEQ * HD;  // [64,2048,64]
  u16* VtG  = Kg  + (size_t)BATCH * HEADS * SEQ * HD;  // [64,64,2048]
  u16* ctxh = VtG + (size_t)BATCH * HEADS * HD * SEQ;  // [8192,1024]

  conv_x<<<ROWS * DIM / 4 / 256, 256, 0, stream>>>(x, xh);
  conv_w<<<dim3(QKV_N / 64, DIM / 64), 256, 0, stream>>>(Wqkv, Wqt, DIM, QKV_N);
  conv_w<<<dim3(DIM / 64, DIM / 64), 256, 0, stream>>>(Wout, Wot, DIM, DIM);

  // 1) qkv = x @ Wqkv (fp16 MFMA), repack -> Qg (×ATT_C) / Kg / VtG
  gemm_bt<1><<<dim3(QKV_N / 128, ROWS / 128), 256, 0, stream>>>(
      xh, Wqt, nullptr, nullptr, Qg, Kg, VtG, ROWS, QKV_N, DIM);

  // 2) attention -> ctxh (fp16): 8 waves, j-tile 128, 2 blocks/CU exact
  attn_mfma<<<dim3(1024), 512, 0, stream>>>(Qg, Kg, VtG, ctxh);

  // 3) out = ctx @ Wout + bout (fp32)
  gemm_bt<0><<<dim3(DIM / 128, ROWS / 128), 256, 0, stream>>>(
      ctxh, Wot, bout, out, nullptr, nullptr, nullptr, ROWS, DIM, DIM);
}